// Round 8
// baseline (4087.447 us; speedup 1.0000x reference)
//
#include <hip/hip_runtime.h>
#include <hip/hip_bf16.h>

#define NN 20000
#define NE 640000
#define DSH 9
#define NB 10
#define ATTR 4

typedef __attribute__((ext_vector_type(8))) short bfrag8;  // 8 bf16 (4 VGPR)
typedef __attribute__((ext_vector_type(4))) float f32x4;
typedef unsigned int u32;
typedef unsigned short u16;

constexpr float INV_SQRT_NB = 0.17677669529663687f; // 1/sqrt(32)

// silu via fast rcp: ~2 insts vs ~10 for IEEE divide; rel err 2^-22 << bf16 rounding
__device__ __forceinline__ float silu_f(float x) {
    return x * __builtin_amdgcn_rcpf(1.0f + __expf(-x));
}

__device__ __forceinline__ u16 f2bf(float v) {
    union { __hip_bfloat16 h; u16 u; } c;
    c.h = __float2bfloat16(v);
    return c.u;
}

__device__ __forceinline__ f32x4 mfma16(bfrag8 a, bfrag8 b, f32x4 c) {
    return __builtin_amdgcn_mfma_f32_16x16x32_bf16(a, b, c, 0, 0, 0);
}

// ---------------------------------------------------------------------------
// CSR build over dst; fill_k emits pos[e] = slot so msg can be written
// slot-ordered (gather becomes a sequential stream).  [R4-exact]
// ---------------------------------------------------------------------------
__global__ void count_k(const int* __restrict__ dst, int* __restrict__ cnt) {
    int i = blockIdx.x * blockDim.x + threadIdx.x;
    int st = gridDim.x * blockDim.x;
    for (; i < NE; i += st) atomicAdd(&cnt[dst[i]], 1);
}

__global__ void scan_k(const int* __restrict__ cnt, int* __restrict__ ptr) {
    __shared__ int ssum[256];
    const int T = 256, t = threadIdx.x;
    const int strip = (NN + T - 1) / T;
    int base = t * strip, s = 0;
    for (int i = 0; i < strip; i++) { int idx = base + i; if (idx < NN) s += cnt[idx]; }
    ssum[t] = s; __syncthreads();
    for (int off = 1; off < T; off <<= 1) {
        int v = (t >= off) ? ssum[t - off] : 0;
        __syncthreads();
        ssum[t] += v;
        __syncthreads();
    }
    int run = (t == 0) ? 0 : ssum[t - 1];
    for (int i = 0; i < strip; i++) {
        int idx = base + i;
        if (idx < NN) { int c = cnt[idx]; ptr[idx] = run; run += c; }
    }
    if (t == T - 1) ptr[NN] = run;
}

__global__ void fill_k(const int* __restrict__ dst, const int* __restrict__ ptr,
                       int* __restrict__ cnt, int* __restrict__ pos) {
    int i = blockIdx.x * blockDim.x + threadIdx.x;
    int st = gridDim.x * blockDim.x;
    for (; i < NE; i += st) {
        int d = dst[i];
        int r = atomicAdd(&cnt[d], 1);
        pos[i] = ptr[d] + r;
    }
}

// ---------------------------------------------------------------------------
// Pack a [K][N] f32 weight into MFMA B-fragment tiles (bf16, zero-padded)
// ---------------------------------------------------------------------------
__global__ void pack_bfrag(const float* __restrict__ W, u16* __restrict__ out,
                           int K, int N, int NT, int KS) {
    int tid = blockIdx.x * blockDim.x + threadIdx.x;
    if (tid >= NT * KS * 64) return;
    int l = tid & 63, ts = tid >> 6, s = ts % KS, t = ts / KS;
    int kb = s * 32 + ((l >> 4) << 3);
    int n = t * 16 + (l & 15);
    #pragma unroll
    for (int j = 0; j < 8; j++) {
        int k = kb + j;
        float v = (k < K && n < N) ? W[(size_t)k * N + n] : 0.f;
        out[(size_t)tid * 8 + j] = f2bf(v);
    }
}

// ---------------------------------------------------------------------------
// Per-node prep: xa = x @ A   and   agg = outer(x, attr) @ Wsc  [R4-exact]
// ---------------------------------------------------------------------------
template<int DI, int DO, int NT>
__global__ void node_prep(const float* __restrict__ xin,
                          const float* __restrict__ attr,
                          const float* __restrict__ A,
                          const float* __restrict__ Wsc,
                          float* __restrict__ xa,
                          float* __restrict__ agg)
{
    __shared__ float sx[NT][DI];
    __shared__ float sat[NT][ATTR];
    const int n0 = blockIdx.x * NT;
    for (int idx = threadIdx.x; idx < NT * DI; idx += blockDim.x)
        sx[idx / DI][idx % DI] = xin[(size_t)n0 * DI + idx];
    if (threadIdx.x < NT * ATTR)
        sat[threadIdx.x / ATTR][threadIdx.x % ATTR] = attr[(size_t)n0 * ATTR + threadIdx.x];
    __syncthreads();

    const int o = threadIdx.x;
    if (o < DO) {
        float at[NT][ATTR];
        #pragma unroll
        for (int n = 0; n < NT; n++) {
            at[n][0] = sat[n][0]; at[n][1] = sat[n][1];
            at[n][2] = sat[n][2]; at[n][3] = sat[n][3];
        }
        float accA[NT], accS[NT];
        #pragma unroll
        for (int n = 0; n < NT; n++) { accA[n] = 0.f; accS[n] = 0.f; }
        for (int i = 0; i < DI; i++) {
            float a  = A[(size_t)i * DO + o];
            float w0 = Wsc[(size_t)(i * 4 + 0) * DO + o];
            float w1 = Wsc[(size_t)(i * 4 + 1) * DO + o];
            float w2 = Wsc[(size_t)(i * 4 + 2) * DO + o];
            float w3 = Wsc[(size_t)(i * 4 + 3) * DO + o];
            #pragma unroll
            for (int n = 0; n < NT; n++) {
                float xi = sx[n][i];
                accA[n] = fmaf(xi, a, accA[n]);
                float s = fmaf(at[n][3], w3,
                          fmaf(at[n][2], w2,
                          fmaf(at[n][1], w1, at[n][0] * w0)));
                accS[n] = fmaf(xi, s, accS[n]);
            }
        }
        #pragma unroll
        for (int n = 0; n < NT; n++) {
            xa [(size_t)(n0 + n) * DO + o] = accA[n];
            agg[(size_t)(n0 + n) * DO + o] = accS[n];
        }
    }
}

// ---------------------------------------------------------------------------
// MFMA edge kernel. R7 numerics; changes:
//  (a) xa gather staged into LDS as bf16 (xaL[16][73] dw) via coalesced
//      float2 loads issued BEFORE phase A — latency overlaps A+B, and the
//      36 persistent xv VGPRs become a transient peak.
//  (b) __launch_bounds__(256,3): VGPR cap 170 -> 3 waves/SIMD.
//  (c) silu via v_rcp_f32.
// Per-wave LDS layout (3248 dw):
//   0..1167   xaL[16][73] (dw = 2 bf16); 0..303 doubles as embL/shL until
//             the A/sh fragment builds complete (xaL fill happens after)
//   1168..1679 h1dw[16][32]
//   1680..3215 h2dw[16][64], reused as msg[16][96]
//   3216..3231 sidxL ; 3232..3247 posL
// Fragment layouts: A row=lane&15,k=(lane>>4)*8+j ; C/D col=lane&15,row=(lane>>4)*4+reg
// ---------------------------------------------------------------------------
template<int DO>
__global__ void __launch_bounds__(256, 3)
edge_mfma(const float* __restrict__ emb, const float* __restrict__ sh,
          const int* __restrict__ src, const int* __restrict__ pos,
          const u16* __restrict__ W1f, const u16* __restrict__ W2f,
          const u16* __restrict__ W3f, const u16* __restrict__ Bf,
          const float* __restrict__ xa, u32* __restrict__ msgdw,
          float* __restrict__ msg3)
{
    __shared__ u32 ldsa[4 * 3248];        // 12992 B per wave, 51968 B/block
    const int wid = threadIdx.x >> 6;
    const int l   = threadIdx.x & 63;
    u32* Wl = ldsa + wid * 3248;
    u32*   xaLw  = Wl;                    // [16][73] dw (bf16 pairs)
    float* embL  = (float*)Wl;            // [16][10] f32 (dw 0..159, dies at frag build)
    float* shL   = (float*)(Wl + 160);    // [16][9]  f32 (dw 160..303, dies at frag build)
    u32*   h1dw  = Wl + 1168;             // [16][32] dw
    u32*   h2dw  = Wl + 1680;             // [16][64] dw h2, reused as [16][96] dw msg
    int*   sidxL = (int*)(Wl + 3216);     // [16]
    int*   posL  = (int*)(Wl + 3232);     // [16]

    const bfrag8* w1f = (const bfrag8*)W1f;
    const bfrag8* w2f = (const bfrag8*)W2f;
    const bfrag8* w3f = (const bfrag8*)W3f;
    const bfrag8* bff = (const bfrag8*)Bf;

    const int g = l >> 4, c = l & 15;
    const int gwave = blockIdx.x * 4 + wid;
    const int nwave = gridDim.x * 4;
    const f32x4 Z4 = {0.f, 0.f, 0.f, 0.f};

    for (int it = gwave; it < NE / 16; it += nwave) {
        const int e0 = it * 16;
        // ---- stage emb/sh/idx (direct global->LDS) ----
        {
            const float* ep = emb + (size_t)e0 * NB;
            for (int idx = l; idx < 16 * NB; idx += 64) embL[idx] = ep[idx];
            const float* sp = sh + (size_t)e0 * DSH;
            for (int idx = l; idx < 16 * DSH; idx += 64) shL[idx] = sp[idx];
            if (l < 16) { sidxL[l] = src[e0 + l]; posL[l] = pos[e0 + l]; }
        }
        // ---- A-frags of emb and sh (embL/shL die after this) ----
        bfrag8 a_emb, a_sh;
        {
            const int kb = g << 3;
            #pragma unroll
            for (int j = 0; j < 8; j++) {
                int k = kb + j;
                a_emb[j] = (short)((k < NB)  ? f2bf(embL[c * NB + k])  : (u16)0);
                a_sh[j]  = (short)((k < DSH) ? f2bf(shL[c * DSH + k]) : (u16)0);
            }
        }
        // ---- xa gather -> xaL (bf16), coalesced float2 loads issued early ----
        if constexpr (DO == 144) {
            #pragma unroll
            for (int i = 0; i < 18; i++) {
                int idx = i * 64 + l;                 // 0..1151
                int m = idx / 72, q = idx - m * 72;   // row, packed-dw col
                const float2 v = *(const float2*)&xa[(size_t)sidxL[m] * 144 + 2 * q];
                __hip_bfloat162 b = __float22bfloat162_rn(v);
                xaLw[m * 73 + q] = *(const u32*)&b;
            }
        }
        // ---- phase A: h1 = silu(emb @ W1), 4 MFMA -> LDS ----
        #pragma unroll
        for (int t = 0; t < 4; t++) {
            f32x4 acc = mfma16(a_emb, w1f[t * 64 + l], Z4);
            #pragma unroll
            for (int r = 0; r < 4; r++) {
                int m = g * 4 + r, n = t * 16 + c;
                int dw = (m * 32 + (n >> 1)) ^ ((m & 7) << 2);
                ((u16*)(h1dw + dw))[n & 1] = f2bf(silu_f(acc[r]));
            }
        }
        bfrag8 a_h1_0, a_h1_1;
        {
            int bb = c * 32 + g * 4, xr = (c & 7) << 2;
            a_h1_0 = *(const bfrag8*)(h1dw + ((bb +  0) ^ xr));
            a_h1_1 = *(const bfrag8*)(h1dw + ((bb + 16) ^ xr));
        }
        // ---- phase B: h2 = silu(h1 @ W2), 16 MFMA -> LDS ----
        #pragma unroll
        for (int t2 = 0; t2 < 8; t2++) {
            f32x4 acc = mfma16(a_h1_0, w2f[(t2 * 2 + 0) * 64 + l], Z4);
            acc = mfma16(a_h1_1, w2f[(t2 * 2 + 1) * 64 + l], acc);
            #pragma unroll
            for (int r = 0; r < 4; r++) {
                int m = g * 4 + r, n = t2 * 16 + c;
                int dw = (m * 64 + (n >> 1)) ^ ((m & 7) << 2);
                ((u16*)(h2dw + dw))[n & 1] = f2bf(silu_f(acc[r]));
            }
        }
        bfrag8 a_h2_0, a_h2_1, a_h2_2, a_h2_3;
        {
            int bb = c * 64 + g * 4, xr = (c & 7) << 2;
            a_h2_0 = *(const bfrag8*)(h2dw + ((bb +  0) ^ xr));
            a_h2_1 = *(const bfrag8*)(h2dw + ((bb + 16) ^ xr));
            a_h2_2 = *(const bfrag8*)(h2dw + ((bb + 32) ^ xr));
            a_h2_3 = *(const bfrag8*)(h2dw + ((bb + 48) ^ xr));
        }

        if constexpr (DO == 144) {
            const u16* xaL16 = (const u16*)xaLw;
            // ---- phases C+D per 16-col tile; xa values read from xaL ----
            #pragma unroll
            for (int t3 = 0; t3 < 9; t3++) {
                f32x4 shb = mfma16(a_sh, bff[t3 * 64 + l], Z4);
                f32x4 acc = mfma16(a_h2_0, w3f[(t3 * 4 + 0) * 64 + l], Z4);
                acc = mfma16(a_h2_1, w3f[(t3 * 4 + 1) * 64 + l], acc);
                acc = mfma16(a_h2_2, w3f[(t3 * 4 + 2) * 64 + l], acc);
                acc = mfma16(a_h2_3, w3f[(t3 * 4 + 3) * 64 + l], acc);
                const int n = t3 * 16 + c;
                const int nq = (n >> 1), nb = (n & 1);
                const int m0 = g * 4;
                float x0 = __uint_as_float((u32)xaL16[((m0 + 0) * 73 + nq) * 2 + nb] << 16);
                float x1 = __uint_as_float((u32)xaL16[((m0 + 1) * 73 + nq) * 2 + nb] << 16);
                float x2 = __uint_as_float((u32)xaL16[((m0 + 2) * 73 + nq) * 2 + nb] << 16);
                float x3 = __uint_as_float((u32)xaL16[((m0 + 3) * 73 + nq) * 2 + nb] << 16);
                float v0 = acc[0] * shb[0] * x0 * INV_SQRT_NB;
                float v1 = acc[1] * shb[1] * x1 * INV_SQRT_NB;
                float v2 = acc[2] * shb[2] * x2 * INV_SQRT_NB;
                float v3 = acc[3] * shb[3] * x3 * INV_SQRT_NB;
                int d0 = ((m0 + 0) * 96 + nq) ^ (((m0 + 0) & 7) << 2);
                int d1 = ((m0 + 1) * 96 + nq) ^ (((m0 + 1) & 7) << 2);
                int d2 = ((m0 + 2) * 96 + nq) ^ (((m0 + 2) & 7) << 2);
                int d3 = ((m0 + 3) * 96 + nq) ^ (((m0 + 3) & 7) << 2);
                ((u16*)(h2dw + d0))[nb] = f2bf(v0);
                ((u16*)(h2dw + d1))[nb] = f2bf(v1);
                ((u16*)(h2dw + d2))[nb] = f2bf(v2);
                ((u16*)(h2dw + d3))[nb] = f2bf(v3);
            }
            // ---- coalesced copy-out, slot-ordered rows ----
            for (int i = l; i < 1152; i += 64) {
                int m = i / 72;
                int xq = i - m * 72;
                u32 v = h2dw[(m * 96 + xq) ^ ((m & 7) << 2)];
                msgdw[(size_t)posL[m] * 72 + xq] = v;
            }
        } else {
            // ---- DO==3: single padded N-tile, direct f32 stores ----
            const int si0 = sidxL[g * 4 + 0], si1 = sidxL[g * 4 + 1];
            const int si2 = sidxL[g * 4 + 2], si3 = sidxL[g * 4 + 3];
            const int p0 = posL[g * 4 + 0], p1 = posL[g * 4 + 1];
            const int p2 = posL[g * 4 + 2], p3 = posL[g * 4 + 3];
            f32x4 shb = mfma16(a_sh, bff[l], Z4);
            f32x4 acc = mfma16(a_h2_0, w3f[0 * 64 + l], Z4);
            acc = mfma16(a_h2_1, w3f[1 * 64 + l], acc);
            acc = mfma16(a_h2_2, w3f[2 * 64 + l], acc);
            acc = mfma16(a_h2_3, w3f[3 * 64 + l], acc);
            if (c < 3) {
                msg3[(size_t)p0 * 3 + c] = acc[0] * shb[0] * xa[(size_t)si0 * 3 + c] * INV_SQRT_NB;
                msg3[(size_t)p1 * 3 + c] = acc[1] * shb[1] * xa[(size_t)si1 * 3 + c] * INV_SQRT_NB;
                msg3[(size_t)p2 * 3 + c] = acc[2] * shb[2] * xa[(size_t)si2 * 3 + c] * INV_SQRT_NB;
                msg3[(size_t)p3 * 3 + c] = acc[3] * shb[3] * xa[(size_t)si3 * 3 + c] * INV_SQRT_NB;
            }
        }
    }
}

// ---------------------------------------------------------------------------
// Streaming gather: msg is slot-ordered; node n's messages are rows
// ptr[n]..ptr[n+1] — fully sequential reads. Wave per node.  [R4-exact]
// ---------------------------------------------------------------------------
template<int ACT>
__global__ void gather144(const u32* __restrict__ msgdw,
                          const int* __restrict__ ptr,
                          const float* __restrict__ sc,
                          float* __restrict__ outb)
{
    const int lane = threadIdx.x & 63;
    const int gw = blockIdx.x * (blockDim.x >> 6) + (threadIdx.x >> 6);
    const int nw = gridDim.x * (blockDim.x >> 6);
    for (int n = gw; n < NN; n += nw) {
        const int s0 = ptr[n], s1 = ptr[n + 1];
        float a0 = 0.f, a1 = 0.f, b0 = 0.f, b1 = 0.f;
        for (int s = s0; s < s1; s++) {
            u32 u = msgdw[(size_t)s * 72 + lane];
            a0 += __uint_as_float(u << 16);
            a1 += __uint_as_float(u & 0xffff0000u);
            if (lane < 8) {
                u32 v = msgdw[(size_t)s * 72 + 64 + lane];
                b0 += __uint_as_float(v << 16);
                b1 += __uint_as_float(v & 0xffff0000u);
            }
        }
        size_t base = (size_t)n * 144;
        float2 sv = *(const float2*)&sc[base + 2 * lane];
        float v0 = sv.x + a0, v1 = sv.y + a1;
        if (ACT) { v0 = silu_f(v0); v1 = silu_f(v1); }
        *(float2*)&outb[base + 2 * lane] = make_float2(v0, v1);
        if (lane < 8) {
            float2 sw = *(const float2*)&sc[base + 128 + 2 * lane];
            float w0 = sw.x + b0, w1 = sw.y + b1;
            if (ACT) { w0 = silu_f(w0); w1 = silu_f(w1); }
            *(float2*)&outb[base + 128 + 2 * lane] = make_float2(w0, w1);
        }
    }
}

__global__ void gather3(const float* __restrict__ msg3,
                        const int* __restrict__ ptr,
                        float* __restrict__ outb)
{
    int t = blockIdx.x * blockDim.x + threadIdx.x;
    if (t >= NN * 3) return;
    int n = t / 3, o = t - 3 * n;
    float a = 0.f;
    for (int s = ptr[n]; s < ptr[n + 1]; s++) a += msg3[(size_t)s * 3 + o];
    outb[t] += a;   // self-connection already written by node_prep
}

// ---------------------------------------------------------------------------
extern "C" void kernel_launch(void* const* d_in, const int* in_sizes, int n_in,
                              void* d_out, int out_size, void* d_ws, size_t ws_size,
                              hipStream_t stream) {
    const float* x    = (const float*)d_in[0];
    const float* attr = (const float*)d_in[1];
    const float* sh   = (const float*)d_in[2];
    const float* emb  = (const float*)d_in[3];
    const float* A0   = (const float*)d_in[4];
    const float* B0   = (const float*)d_in[5];
    const float* W1_0 = (const float*)d_in[6];
    const float* W2_0 = (const float*)d_in[7];
    const float* W3_0 = (const float*)d_in[8];
    const float* Wsc0 = (const float*)d_in[9];
    const float* A1   = (const float*)d_in[10];
    const float* B1   = (const float*)d_in[11];
    const float* W1_1 = (const float*)d_in[12];
    const float* W2_1 = (const float*)d_in[13];
    const float* W3_1 = (const float*)d_in[14];
    const float* Wsc1 = (const float*)d_in[15];
    const float* A2   = (const float*)d_in[16];
    const float* B2   = (const float*)d_in[17];
    const float* W1_2 = (const float*)d_in[18];
    const float* W2_2 = (const float*)d_in[19];
    const float* W3_2 = (const float*)d_in[20];
    const float* Wsc2 = (const float*)d_in[21];
    const int*   src  = (const int*)d_in[22];
    const int*   dst  = (const int*)d_in[23];
    float* out = (float*)d_out;

    // ---- carve workspace (R4-exact) ----
    char* wp = (char*)d_ws;
    auto alloc = [&](size_t bytes) -> void* {
        void* r = (void*)wp;
        wp += (bytes + 255) & ~(size_t)255;
        return r;
    };
    float* xa   = (float*)alloc((size_t)NN * 144 * 4);
    float* agg  = (float*)alloc((size_t)NN * 144 * 4);
    float* hb0  = (float*)alloc((size_t)NN * 144 * 4);
    float* hb1  = (float*)alloc((size_t)NN * 144 * 4);
    int*   cnt  = (int*)alloc((size_t)NN * 4);
    int*   ptr  = (int*)alloc((size_t)(NN + 1) * 4);
    int*   pos  = (int*)alloc((size_t)NE * 4);
    u16* w1f0 = (u16*)alloc(4 * 64 * 8 * 2);
    u16* w2f0 = (u16*)alloc(16 * 64 * 8 * 2);
    u16* w3f0 = (u16*)alloc(36 * 64 * 8 * 2);
    u16* bf0  = (u16*)alloc(9 * 64 * 8 * 2);
    u16* w1f1 = (u16*)alloc(4 * 64 * 8 * 2);
    u16* w2f1 = (u16*)alloc(16 * 64 * 8 * 2);
    u16* w3f1 = (u16*)alloc(36 * 64 * 8 * 2);
    u16* bf1  = (u16*)alloc(9 * 64 * 8 * 2);
    u16* w1f2 = (u16*)alloc(4 * 64 * 8 * 2);
    u16* w2f2 = (u16*)alloc(16 * 64 * 8 * 2);
    u16* w3f2 = (u16*)alloc(4 * 64 * 8 * 2);
    u16* bf2  = (u16*)alloc(1 * 64 * 8 * 2);
    void* msgbuf = alloc((size_t)NE * 288);      // bf16 [E][144] == u32 [E][72]
    u32*   msgdw = (u32*)msgbuf;
    float* msg3  = (float*)msgbuf;               // layer-2 f32 [E][3] aliases

    // ---- CSR build (dst identical across layers) ----
    hipMemsetAsync(cnt, 0, (size_t)NN * 4, stream);
    count_k<<<1024, 256, 0, stream>>>(dst, cnt);
    scan_k<<<1, 256, 0, stream>>>(cnt, ptr);
    hipMemsetAsync(cnt, 0, (size_t)NN * 4, stream);
    fill_k<<<1024, 256, 0, stream>>>(dst, ptr, cnt, pos);

    // ---- weight fragment packing ----
    pack_bfrag<<<1, 256, 0, stream>>>(W1_0, w1f0, 10, 64, 4, 1);
    pack_bfrag<<<4, 256, 0, stream>>>(W2_0, w2f0, 64, 128, 8, 2);
    pack_bfrag<<<9, 256, 0, stream>>>(W3_0, w3f0, 128, 144, 9, 4);
    pack_bfrag<<<3, 256, 0, stream>>>(B0,   bf0,  9, 144, 9, 1);
    pack_bfrag<<<1, 256, 0, stream>>>(W1_1, w1f1, 10, 64, 4, 1);
    pack_bfrag<<<4, 256, 0, stream>>>(W2_1, w2f1, 64, 128, 8, 2);
    pack_bfrag<<<9, 256, 0, stream>>>(W3_1, w3f1, 128, 144, 9, 4);
    pack_bfrag<<<3, 256, 0, stream>>>(B1,   bf1,  9, 144, 9, 1);
    pack_bfrag<<<1, 256, 0, stream>>>(W1_2, w1f2, 10, 64, 4, 1);
    pack_bfrag<<<4, 256, 0, stream>>>(W2_2, w2f2, 64, 128, 8, 2);
    pack_bfrag<<<1, 256, 0, stream>>>(W3_2, w3f2, 128, 3, 1, 4);
    pack_bfrag<<<1, 256, 0, stream>>>(B2,   bf2,  9, 3, 1, 1);

    // ---- layer 0 (di=64, do=144) ----
    node_prep<64, 144, 8><<<NN / 8, 192, 0, stream>>>(x, attr, A0, Wsc0, xa, agg);
    edge_mfma<144><<<2500, 256, 0, stream>>>(emb, sh, src, pos, w1f0, w2f0, w3f0, bf0, xa, msgdw, nullptr);
    gather144<1><<<5000, 256, 0, stream>>>(msgdw, ptr, agg, hb0);

    // ---- layer 1 (di=144, do=144) ----
    node_prep<144, 144, 8><<<NN / 8, 192, 0, stream>>>(hb0, attr, A1, Wsc1, xa, agg);
    edge_mfma<144><<<2500, 256, 0, stream>>>(emb, sh, src, pos, w1f1, w2f1, w3f1, bf1, xa, msgdw, nullptr);
    gather144<1><<<5000, 256, 0, stream>>>(msgdw, ptr, agg, hb1);

    // ---- layer 2 (di=144, do=3) ----
    node_prep<144, 3, 8><<<NN / 8, 192, 0, stream>>>(hb1, attr, A2, Wsc2, xa, out);
    edge_mfma<3><<<2500, 256, 0, stream>>>(emb, sh, src, pos, w1f2, w2f2, w3f2, bf2, xa, nullptr, msg3);
    gather3<<<(NN * 3 + 255) / 256, 256, 0, stream>>>(msg3, ptr, out);
}

// Round 9
// 1883.242 us; speedup vs baseline: 2.1704x; 2.1704x over previous
//
#include <hip/hip_runtime.h>
#include <hip/hip_bf16.h>

#define NN 20000
#define NE 640000
#define DSH 9
#define NB 10
#define ATTR 4

typedef __attribute__((ext_vector_type(8))) short bfrag8;  // 8 bf16 (4 VGPR)
typedef __attribute__((ext_vector_type(4))) float f32x4;
typedef unsigned int u32;
typedef unsigned short u16;

constexpr float INV_SQRT_NB = 0.17677669529663687f; // 1/sqrt(32)

// silu via fast rcp: ~2 insts vs ~10 for IEEE divide; rel err 2^-22 << bf16 rounding
__device__ __forceinline__ float silu_f(float x) {
    return x * __builtin_amdgcn_rcpf(1.0f + __expf(-x));
}

__device__ __forceinline__ u16 f2bf(float v) {
    union { __hip_bfloat16 h; u16 u; } c;
    c.h = __float2bfloat16(v);
    return c.u;
}

__device__ __forceinline__ f32x4 mfma16(bfrag8 a, bfrag8 b, f32x4 c) {
    return __builtin_amdgcn_mfma_f32_16x16x32_bf16(a, b, c, 0, 0, 0);
}

// ---------------------------------------------------------------------------
// CSR build over dst; fill_k emits pos[e] = slot so msg can be written
// slot-ordered (gather becomes a sequential stream).
// ---------------------------------------------------------------------------
__global__ void count_k(const int* __restrict__ dst, int* __restrict__ cnt) {
    int i = blockIdx.x * blockDim.x + threadIdx.x;
    int st = gridDim.x * blockDim.x;
    for (; i < NE; i += st) atomicAdd(&cnt[dst[i]], 1);
}

__global__ void scan_k(const int* __restrict__ cnt, int* __restrict__ ptr) {
    __shared__ int ssum[256];
    const int T = 256, t = threadIdx.x;
    const int strip = (NN + T - 1) / T;
    int base = t * strip, s = 0;
    for (int i = 0; i < strip; i++) { int idx = base + i; if (idx < NN) s += cnt[idx]; }
    ssum[t] = s; __syncthreads();
    for (int off = 1; off < T; off <<= 1) {
        int v = (t >= off) ? ssum[t - off] : 0;
        __syncthreads();
        ssum[t] += v;
        __syncthreads();
    }
    int run = (t == 0) ? 0 : ssum[t - 1];
    for (int i = 0; i < strip; i++) {
        int idx = base + i;
        if (idx < NN) { int c = cnt[idx]; ptr[idx] = run; run += c; }
    }
    if (t == T - 1) ptr[NN] = run;
}

__global__ void fill_k(const int* __restrict__ dst, const int* __restrict__ ptr,
                       int* __restrict__ cnt, int* __restrict__ pos) {
    int i = blockIdx.x * blockDim.x + threadIdx.x;
    int st = gridDim.x * blockDim.x;
    for (; i < NE; i += st) {
        int d = dst[i];
        int r = atomicAdd(&cnt[d], 1);
        pos[i] = ptr[d] + r;
    }
}

// ---------------------------------------------------------------------------
// Pack a [K][N] f32 weight into MFMA B-fragment tiles (bf16, zero-padded)
// ---------------------------------------------------------------------------
__global__ void pack_bfrag(const float* __restrict__ W, u16* __restrict__ out,
                           int K, int N, int NT, int KS) {
    int tid = blockIdx.x * blockDim.x + threadIdx.x;
    if (tid >= NT * KS * 64) return;
    int l = tid & 63, ts = tid >> 6, s = ts % KS, t = ts / KS;
    int kb = s * 32 + ((l >> 4) << 3);
    int n = t * 16 + (l & 15);
    #pragma unroll
    for (int j = 0; j < 8; j++) {
        int k = kb + j;
        float v = (k < K && n < N) ? W[(size_t)k * N + n] : 0.f;
        out[(size_t)tid * 8 + j] = f2bf(v);
    }
}

// ---------------------------------------------------------------------------
// Per-node prep: xa = x @ A   and   agg = outer(x, attr) @ Wsc
// ---------------------------------------------------------------------------
template<int DI, int DO, int NT>
__global__ void node_prep(const float* __restrict__ xin,
                          const float* __restrict__ attr,
                          const float* __restrict__ A,
                          const float* __restrict__ Wsc,
                          float* __restrict__ xa,
                          float* __restrict__ agg)
{
    __shared__ float sx[NT][DI];
    __shared__ float sat[NT][ATTR];
    const int n0 = blockIdx.x * NT;
    for (int idx = threadIdx.x; idx < NT * DI; idx += blockDim.x)
        sx[idx / DI][idx % DI] = xin[(size_t)n0 * DI + idx];
    if (threadIdx.x < NT * ATTR)
        sat[threadIdx.x / ATTR][threadIdx.x % ATTR] = attr[(size_t)n0 * ATTR + threadIdx.x];
    __syncthreads();

    const int o = threadIdx.x;
    if (o < DO) {
        float at[NT][ATTR];
        #pragma unroll
        for (int n = 0; n < NT; n++) {
            at[n][0] = sat[n][0]; at[n][1] = sat[n][1];
            at[n][2] = sat[n][2]; at[n][3] = sat[n][3];
        }
        float accA[NT], accS[NT];
        #pragma unroll
        for (int n = 0; n < NT; n++) { accA[n] = 0.f; accS[n] = 0.f; }
        for (int i = 0; i < DI; i++) {
            float a  = A[(size_t)i * DO + o];
            float w0 = Wsc[(size_t)(i * 4 + 0) * DO + o];
            float w1 = Wsc[(size_t)(i * 4 + 1) * DO + o];
            float w2 = Wsc[(size_t)(i * 4 + 2) * DO + o];
            float w3 = Wsc[(size_t)(i * 4 + 3) * DO + o];
            #pragma unroll
            for (int n = 0; n < NT; n++) {
                float xi = sx[n][i];
                accA[n] = fmaf(xi, a, accA[n]);
                float s = fmaf(at[n][3], w3,
                          fmaf(at[n][2], w2,
                          fmaf(at[n][1], w1, at[n][0] * w0)));
                accS[n] = fmaf(xi, s, accS[n]);
            }
        }
        #pragma unroll
        for (int n = 0; n < NT; n++) {
            xa [(size_t)(n0 + n) * DO + o] = accA[n];
            agg[(size_t)(n0 + n) * DO + o] = accS[n];
        }
    }
}

// ---------------------------------------------------------------------------
// MFMA edge kernel. R8-exact numerics; schedule changes only:
//  (a) plain __launch_bounds__(256) — (256,3) forced VGPR=84 -> 3.5 GB of
//      spill traffic (R8). NEVER use min-waves > 2 here; VGPR must float.
//  (b) t3 loop `#pragma unroll 3` — full unroll made the compiler hoist all
//      45 weight fragments (~180 VGPR, R7=252); 3-deep keeps ~15 in flight.
//      xa values come from LDS (xaL), so dynamic t3 indexing is safe.
// Per-wave LDS layout (3248 dw):
//   0..1167   xaL[16][73] (dw = 2 bf16); 0..303 doubles as embL/shL until
//             the A/sh fragment builds complete (xaL fill happens after)
//   1168..1679 h1dw[16][32]
//   1680..3215 h2dw[16][64], reused as msg[16][96]
//   3216..3231 sidxL ; 3232..3247 posL
// Fragment layouts: A row=lane&15,k=(lane>>4)*8+j ; C/D col=lane&15,row=(lane>>4)*4+reg
// ---------------------------------------------------------------------------
template<int DO>
__global__ void __launch_bounds__(256)
edge_mfma(const float* __restrict__ emb, const float* __restrict__ sh,
          const int* __restrict__ src, const int* __restrict__ pos,
          const u16* __restrict__ W1f, const u16* __restrict__ W2f,
          const u16* __restrict__ W3f, const u16* __restrict__ Bf,
          const float* __restrict__ xa, u32* __restrict__ msgdw,
          float* __restrict__ msg3)
{
    __shared__ u32 ldsa[4 * 3248];        // 12992 B per wave, 51968 B/block
    const int wid = threadIdx.x >> 6;
    const int l   = threadIdx.x & 63;
    u32* Wl = ldsa + wid * 3248;
    u32*   xaLw  = Wl;                    // [16][73] dw (bf16 pairs)
    float* embL  = (float*)Wl;            // [16][10] f32 (dw 0..159, dies at frag build)
    float* shL   = (float*)(Wl + 160);    // [16][9]  f32 (dw 160..303, dies at frag build)
    u32*   h1dw  = Wl + 1168;             // [16][32] dw
    u32*   h2dw  = Wl + 1680;             // [16][64] dw h2, reused as [16][96] dw msg
    int*   sidxL = (int*)(Wl + 3216);     // [16]
    int*   posL  = (int*)(Wl + 3232);     // [16]

    const bfrag8* w1f = (const bfrag8*)W1f;
    const bfrag8* w2f = (const bfrag8*)W2f;
    const bfrag8* w3f = (const bfrag8*)W3f;
    const bfrag8* bff = (const bfrag8*)Bf;

    const int g = l >> 4, c = l & 15;
    const int gwave = blockIdx.x * 4 + wid;
    const int nwave = gridDim.x * 4;
    const f32x4 Z4 = {0.f, 0.f, 0.f, 0.f};

    for (int it = gwave; it < NE / 16; it += nwave) {
        const int e0 = it * 16;
        // ---- stage emb/sh/idx (direct global->LDS) ----
        {
            const float* ep = emb + (size_t)e0 * NB;
            for (int idx = l; idx < 16 * NB; idx += 64) embL[idx] = ep[idx];
            const float* sp = sh + (size_t)e0 * DSH;
            for (int idx = l; idx < 16 * DSH; idx += 64) shL[idx] = sp[idx];
            if (l < 16) { sidxL[l] = src[e0 + l]; posL[l] = pos[e0 + l]; }
        }
        // ---- A-frags of emb and sh (embL/shL die after this) ----
        bfrag8 a_emb, a_sh;
        {
            const int kb = g << 3;
            #pragma unroll
            for (int j = 0; j < 8; j++) {
                int k = kb + j;
                a_emb[j] = (short)((k < NB)  ? f2bf(embL[c * NB + k])  : (u16)0);
                a_sh[j]  = (short)((k < DSH) ? f2bf(shL[c * DSH + k]) : (u16)0);
            }
        }
        // ---- xa gather -> xaL (bf16), coalesced float2 loads issued early ----
        if constexpr (DO == 144) {
            #pragma unroll
            for (int i = 0; i < 18; i++) {
                int idx = i * 64 + l;                 // 0..1151
                int m = idx / 72, q = idx - m * 72;   // row, packed-dw col
                const float2 v = *(const float2*)&xa[(size_t)sidxL[m] * 144 + 2 * q];
                __hip_bfloat162 b = __float22bfloat162_rn(v);
                xaLw[m * 73 + q] = *(const u32*)&b;
            }
        }
        // ---- phase A: h1 = silu(emb @ W1), 4 MFMA -> LDS ----
        #pragma unroll
        for (int t = 0; t < 4; t++) {
            f32x4 acc = mfma16(a_emb, w1f[t * 64 + l], Z4);
            #pragma unroll
            for (int r = 0; r < 4; r++) {
                int m = g * 4 + r, n = t * 16 + c;
                int dw = (m * 32 + (n >> 1)) ^ ((m & 7) << 2);
                ((u16*)(h1dw + dw))[n & 1] = f2bf(silu_f(acc[r]));
            }
        }
        bfrag8 a_h1_0, a_h1_1;
        {
            int bb = c * 32 + g * 4, xr = (c & 7) << 2;
            a_h1_0 = *(const bfrag8*)(h1dw + ((bb +  0) ^ xr));
            a_h1_1 = *(const bfrag8*)(h1dw + ((bb + 16) ^ xr));
        }
        // ---- phase B: h2 = silu(h1 @ W2), 16 MFMA -> LDS ----
        #pragma unroll
        for (int t2 = 0; t2 < 8; t2++) {
            f32x4 acc = mfma16(a_h1_0, w2f[(t2 * 2 + 0) * 64 + l], Z4);
            acc = mfma16(a_h1_1, w2f[(t2 * 2 + 1) * 64 + l], acc);
            #pragma unroll
            for (int r = 0; r < 4; r++) {
                int m = g * 4 + r, n = t2 * 16 + c;
                int dw = (m * 64 + (n >> 1)) ^ ((m & 7) << 2);
                ((u16*)(h2dw + dw))[n & 1] = f2bf(silu_f(acc[r]));
            }
        }
        bfrag8 a_h2_0, a_h2_1, a_h2_2, a_h2_3;
        {
            int bb = c * 64 + g * 4, xr = (c & 7) << 2;
            a_h2_0 = *(const bfrag8*)(h2dw + ((bb +  0) ^ xr));
            a_h2_1 = *(const bfrag8*)(h2dw + ((bb + 16) ^ xr));
            a_h2_2 = *(const bfrag8*)(h2dw + ((bb + 32) ^ xr));
            a_h2_3 = *(const bfrag8*)(h2dw + ((bb + 48) ^ xr));
        }

        if constexpr (DO == 144) {
            const u16* xaL16 = (const u16*)xaLw;
            // ---- phases C+D per 16-col tile; xa values read from xaL ----
            #pragma unroll 3
            for (int t3 = 0; t3 < 9; t3++) {
                f32x4 shb = mfma16(a_sh, bff[t3 * 64 + l], Z4);
                f32x4 acc = mfma16(a_h2_0, w3f[(t3 * 4 + 0) * 64 + l], Z4);
                acc = mfma16(a_h2_1, w3f[(t3 * 4 + 1) * 64 + l], acc);
                acc = mfma16(a_h2_2, w3f[(t3 * 4 + 2) * 64 + l], acc);
                acc = mfma16(a_h2_3, w3f[(t3 * 4 + 3) * 64 + l], acc);
                const int n = t3 * 16 + c;
                const int nq = (n >> 1), nb = (n & 1);
                const int m0 = g * 4;
                float x0 = __uint_as_float((u32)xaL16[((m0 + 0) * 73 + nq) * 2 + nb] << 16);
                float x1 = __uint_as_float((u32)xaL16[((m0 + 1) * 73 + nq) * 2 + nb] << 16);
                float x2 = __uint_as_float((u32)xaL16[((m0 + 2) * 73 + nq) * 2 + nb] << 16);
                float x3 = __uint_as_float((u32)xaL16[((m0 + 3) * 73 + nq) * 2 + nb] << 16);
                float v0 = acc[0] * shb[0] * x0 * INV_SQRT_NB;
                float v1 = acc[1] * shb[1] * x1 * INV_SQRT_NB;
                float v2 = acc[2] * shb[2] * x2 * INV_SQRT_NB;
                float v3 = acc[3] * shb[3] * x3 * INV_SQRT_NB;
                int d0 = ((m0 + 0) * 96 + nq) ^ (((m0 + 0) & 7) << 2);
                int d1 = ((m0 + 1) * 96 + nq) ^ (((m0 + 1) & 7) << 2);
                int d2 = ((m0 + 2) * 96 + nq) ^ (((m0 + 2) & 7) << 2);
                int d3 = ((m0 + 3) * 96 + nq) ^ (((m0 + 3) & 7) << 2);
                ((u16*)(h2dw + d0))[nb] = f2bf(v0);
                ((u16*)(h2dw + d1))[nb] = f2bf(v1);
                ((u16*)(h2dw + d2))[nb] = f2bf(v2);
                ((u16*)(h2dw + d3))[nb] = f2bf(v3);
            }
            // ---- coalesced copy-out, slot-ordered rows ----
            for (int i = l; i < 1152; i += 64) {
                int m = i / 72;
                int xq = i - m * 72;
                u32 v = h2dw[(m * 96 + xq) ^ ((m & 7) << 2)];
                msgdw[(size_t)posL[m] * 72 + xq] = v;
            }
        } else {
            // ---- DO==3: single padded N-tile, direct f32 stores ----
            const int si0 = sidxL[g * 4 + 0], si1 = sidxL[g * 4 + 1];
            const int si2 = sidxL[g * 4 + 2], si3 = sidxL[g * 4 + 3];
            const int p0 = posL[g * 4 + 0], p1 = posL[g * 4 + 1];
            const int p2 = posL[g * 4 + 2], p3 = posL[g * 4 + 3];
            f32x4 shb = mfma16(a_sh, bff[l], Z4);
            f32x4 acc = mfma16(a_h2_0, w3f[0 * 64 + l], Z4);
            acc = mfma16(a_h2_1, w3f[1 * 64 + l], acc);
            acc = mfma16(a_h2_2, w3f[2 * 64 + l], acc);
            acc = mfma16(a_h2_3, w3f[3 * 64 + l], acc);
            if (c < 3) {
                msg3[(size_t)p0 * 3 + c] = acc[0] * shb[0] * xa[(size_t)si0 * 3 + c] * INV_SQRT_NB;
                msg3[(size_t)p1 * 3 + c] = acc[1] * shb[1] * xa[(size_t)si1 * 3 + c] * INV_SQRT_NB;
                msg3[(size_t)p2 * 3 + c] = acc[2] * shb[2] * xa[(size_t)si2 * 3 + c] * INV_SQRT_NB;
                msg3[(size_t)p3 * 3 + c] = acc[3] * shb[3] * xa[(size_t)si3 * 3 + c] * INV_SQRT_NB;
            }
        }
    }
}

// ---------------------------------------------------------------------------
// Streaming gather: msg is slot-ordered; node n's messages are rows
// ptr[n]..ptr[n+1] — fully sequential reads. Wave per node.
// ---------------------------------------------------------------------------
template<int ACT>
__global__ void gather144(const u32* __restrict__ msgdw,
                          const int* __restrict__ ptr,
                          const float* __restrict__ sc,
                          float* __restrict__ outb)
{
    const int lane = threadIdx.x & 63;
    const int gw = blockIdx.x * (blockDim.x >> 6) + (threadIdx.x >> 6);
    const int nw = gridDim.x * (blockDim.x >> 6);
    for (int n = gw; n < NN; n += nw) {
        const int s0 = ptr[n], s1 = ptr[n + 1];
        float a0 = 0.f, a1 = 0.f, b0 = 0.f, b1 = 0.f;
        for (int s = s0; s < s1; s++) {
            u32 u = msgdw[(size_t)s * 72 + lane];
            a0 += __uint_as_float(u << 16);
            a1 += __uint_as_float(u & 0xffff0000u);
            if (lane < 8) {
                u32 v = msgdw[(size_t)s * 72 + 64 + lane];
                b0 += __uint_as_float(v << 16);
                b1 += __uint_as_float(v & 0xffff0000u);
            }
        }
        size_t base = (size_t)n * 144;
        float2 sv = *(const float2*)&sc[base + 2 * lane];
        float v0 = sv.x + a0, v1 = sv.y + a1;
        if (ACT) { v0 = silu_f(v0); v1 = silu_f(v1); }
        *(float2*)&outb[base + 2 * lane] = make_float2(v0, v1);
        if (lane < 8) {
            float2 sw = *(const float2*)&sc[base + 128 + 2 * lane];
            float w0 = sw.x + b0, w1 = sw.y + b1;
            if (ACT) { w0 = silu_f(w0); w1 = silu_f(w1); }
            *(float2*)&outb[base + 128 + 2 * lane] = make_float2(w0, w1);
        }
    }
}

__global__ void gather3(const float* __restrict__ msg3,
                        const int* __restrict__ ptr,
                        float* __restrict__ outb)
{
    int t = blockIdx.x * blockDim.x + threadIdx.x;
    if (t >= NN * 3) return;
    int n = t / 3, o = t - 3 * n;
    float a = 0.f;
    for (int s = ptr[n]; s < ptr[n + 1]; s++) a += msg3[(size_t)s * 3 + o];
    outb[t] += a;   // self-connection already written by node_prep
}

// ---------------------------------------------------------------------------
extern "C" void kernel_launch(void* const* d_in, const int* in_sizes, int n_in,
                              void* d_out, int out_size, void* d_ws, size_t ws_size,
                              hipStream_t stream) {
    const float* x    = (const float*)d_in[0];
    const float* attr = (const float*)d_in[1];
    const float* sh   = (const float*)d_in[2];
    const float* emb  = (const float*)d_in[3];
    const float* A0   = (const float*)d_in[4];
    const float* B0   = (const float*)d_in[5];
    const float* W1_0 = (const float*)d_in[6];
    const float* W2_0 = (const float*)d_in[7];
    const float* W3_0 = (const float*)d_in[8];
    const float* Wsc0 = (const float*)d_in[9];
    const float* A1   = (const float*)d_in[10];
    const float* B1   = (const float*)d_in[11];
    const float* W1_1 = (const float*)d_in[12];
    const float* W2_1 = (const float*)d_in[13];
    const float* W3_1 = (const float*)d_in[14];
    const float* Wsc1 = (const float*)d_in[15];
    const float* A2   = (const float*)d_in[16];
    const float* B2   = (const float*)d_in[17];
    const float* W1_2 = (const float*)d_in[18];
    const float* W2_2 = (const float*)d_in[19];
    const float* W3_2 = (const float*)d_in[20];
    const float* Wsc2 = (const float*)d_in[21];
    const int*   src  = (const int*)d_in[22];
    const int*   dst  = (const int*)d_in[23];
    float* out = (float*)d_out;

    // ---- carve workspace ----
    char* wp = (char*)d_ws;
    auto alloc = [&](size_t bytes) -> void* {
        void* r = (void*)wp;
        wp += (bytes + 255) & ~(size_t)255;
        return r;
    };
    float* xa   = (float*)alloc((size_t)NN * 144 * 4);
    float* agg  = (float*)alloc((size_t)NN * 144 * 4);
    float* hb0  = (float*)alloc((size_t)NN * 144 * 4);
    float* hb1  = (float*)alloc((size_t)NN * 144 * 4);
    int*   cnt  = (int*)alloc((size_t)NN * 4);
    int*   ptr  = (int*)alloc((size_t)(NN + 1) * 4);
    int*   pos  = (int*)alloc((size_t)NE * 4);
    u16* w1f0 = (u16*)alloc(4 * 64 * 8 * 2);
    u16* w2f0 = (u16*)alloc(16 * 64 * 8 * 2);
    u16* w3f0 = (u16*)alloc(36 * 64 * 8 * 2);
    u16* bf0  = (u16*)alloc(9 * 64 * 8 * 2);
    u16* w1f1 = (u16*)alloc(4 * 64 * 8 * 2);
    u16* w2f1 = (u16*)alloc(16 * 64 * 8 * 2);
    u16* w3f1 = (u16*)alloc(36 * 64 * 8 * 2);
    u16* bf1  = (u16*)alloc(9 * 64 * 8 * 2);
    u16* w1f2 = (u16*)alloc(4 * 64 * 8 * 2);
    u16* w2f2 = (u16*)alloc(16 * 64 * 8 * 2);
    u16* w3f2 = (u16*)alloc(4 * 64 * 8 * 2);
    u16* bf2  = (u16*)alloc(1 * 64 * 8 * 2);
    void* msgbuf = alloc((size_t)NE * 288);      // bf16 [E][144] == u32 [E][72]
    u32*   msgdw = (u32*)msgbuf;
    float* msg3  = (float*)msgbuf;               // layer-2 f32 [E][3] aliases

    // ---- CSR build (dst identical across layers) ----
    hipMemsetAsync(cnt, 0, (size_t)NN * 4, stream);
    count_k<<<1024, 256, 0, stream>>>(dst, cnt);
    scan_k<<<1, 256, 0, stream>>>(cnt, ptr);
    hipMemsetAsync(cnt, 0, (size_t)NN * 4, stream);
    fill_k<<<1024, 256, 0, stream>>>(dst, ptr, cnt, pos);

    // ---- weight fragment packing ----
    pack_bfrag<<<1, 256, 0, stream>>>(W1_0, w1f0, 10, 64, 4, 1);
    pack_bfrag<<<4, 256, 0, stream>>>(W2_0, w2f0, 64, 128, 8, 2);
    pack_bfrag<<<9, 256, 0, stream>>>(W3_0, w3f0, 128, 144, 9, 4);
    pack_bfrag<<<3, 256, 0, stream>>>(B0,   bf0,  9, 144, 9, 1);
    pack_bfrag<<<1, 256, 0, stream>>>(W1_1, w1f1, 10, 64, 4, 1);
    pack_bfrag<<<4, 256, 0, stream>>>(W2_1, w2f1, 64, 128, 8, 2);
    pack_bfrag<<<9, 256, 0, stream>>>(W3_1, w3f1, 128, 144, 9, 4);
    pack_bfrag<<<3, 256, 0, stream>>>(B1,   bf1,  9, 144, 9, 1);
    pack_bfrag<<<1, 256, 0, stream>>>(W1_2, w1f2, 10, 64, 4, 1);
    pack_bfrag<<<4, 256, 0, stream>>>(W2_2, w2f2, 64, 128, 8, 2);
    pack_bfrag<<<1, 256, 0, stream>>>(W3_2, w3f2, 128, 3, 1, 4);
    pack_bfrag<<<1, 256, 0, stream>>>(B2,   bf2,  9, 3, 1, 1);

    // ---- layer 0 (di=64, do=144) ----
    node_prep<64, 144, 8><<<NN / 8, 192, 0, stream>>>(x, attr, A0, Wsc0, xa, agg);
    edge_mfma<144><<<2500, 256, 0, stream>>>(emb, sh, src, pos, w1f0, w2f0, w3f0, bf0, xa, msgdw, nullptr);
    gather144<1><<<5000, 256, 0, stream>>>(msgdw, ptr, agg, hb0);

    // ---- layer 1 (di=144, do=144) ----
    node_prep<144, 144, 8><<<NN / 8, 192, 0, stream>>>(hb0, attr, A1, Wsc1, xa, agg);
    edge_mfma<144><<<2500, 256, 0, stream>>>(emb, sh, src, pos, w1f1, w2f1, w3f1, bf1, xa, msgdw, nullptr);
    gather144<1><<<5000, 256, 0, stream>>>(msgdw, ptr, agg, hb1);

    // ---- layer 2 (di=144, do=3) ----
    node_prep<144, 3, 8><<<NN / 8, 192, 0, stream>>>(hb1, attr, A2, Wsc2, xa, out);
    edge_mfma<3><<<2500, 256, 0, stream>>>(emb, sh, src, pos, w1f2, w2f2, w3f2, bf2, xa, nullptr, msg3);
    gather3<<<(NN * 3 + 255) / 256, 256, 0, stream>>>(msg3, ptr, out);
}

// Round 10
// 1186.438 us; speedup vs baseline: 3.4451x; 1.5873x over previous
//
#include <hip/hip_runtime.h>
#include <hip/hip_bf16.h>

#define NN 20000
#define NE 640000
#define DSH 9
#define NB 10
#define ATTR 4

typedef __attribute__((ext_vector_type(8))) short bfrag8;  // 8 bf16 (4 VGPR)
typedef __attribute__((ext_vector_type(4))) float f32x4;
typedef unsigned int u32;
typedef unsigned short u16;

constexpr float INV_SQRT_NB = 0.17677669529663687f; // 1/sqrt(32)

// silu via fast rcp (proven R8/R9): rel err 2^-22 << bf16 rounding
__device__ __forceinline__ float silu_f(float x) {
    return x * __builtin_amdgcn_rcpf(1.0f + __expf(-x));
}

__device__ __forceinline__ u16 f2bf(float v) {
    union { __hip_bfloat16 h; u16 u; } c;
    c.h = __float2bfloat16(v);
    return c.u;
}

__device__ __forceinline__ f32x4 mfma16(bfrag8 a, bfrag8 b, f32x4 c) {
    return __builtin_amdgcn_mfma_f32_16x16x32_bf16(a, b, c, 0, 0, 0);
}

// ---------------------------------------------------------------------------
// CSR build over dst; fill_k emits pos[e] = slot so msg can be written
// slot-ordered (gather becomes a sequential stream).
// ---------------------------------------------------------------------------
__global__ void count_k(const int* __restrict__ dst, int* __restrict__ cnt) {
    int i = blockIdx.x * blockDim.x + threadIdx.x;
    int st = gridDim.x * blockDim.x;
    for (; i < NE; i += st) atomicAdd(&cnt[dst[i]], 1);
}

__global__ void scan_k(const int* __restrict__ cnt, int* __restrict__ ptr) {
    __shared__ int ssum[256];
    const int T = 256, t = threadIdx.x;
    const int strip = (NN + T - 1) / T;
    int base = t * strip, s = 0;
    for (int i = 0; i < strip; i++) { int idx = base + i; if (idx < NN) s += cnt[idx]; }
    ssum[t] = s; __syncthreads();
    for (int off = 1; off < T; off <<= 1) {
        int v = (t >= off) ? ssum[t - off] : 0;
        __syncthreads();
        ssum[t] += v;
        __syncthreads();
    }
    int run = (t == 0) ? 0 : ssum[t - 1];
    for (int i = 0; i < strip; i++) {
        int idx = base + i;
        if (idx < NN) { int c = cnt[idx]; ptr[idx] = run; run += c; }
    }
    if (t == T - 1) ptr[NN] = run;
}

__global__ void fill_k(const int* __restrict__ dst, const int* __restrict__ ptr,
                       int* __restrict__ cnt, int* __restrict__ pos) {
    int i = blockIdx.x * blockDim.x + threadIdx.x;
    int st = gridDim.x * blockDim.x;
    for (; i < NE; i += st) {
        int d = dst[i];
        int r = atomicAdd(&cnt[d], 1);
        pos[i] = ptr[d] + r;
    }
}

// ---------------------------------------------------------------------------
// Pack a [K][N] f32 weight into MFMA B-fragment tiles (bf16, zero-padded)
// ---------------------------------------------------------------------------
__global__ void pack_bfrag(const float* __restrict__ W, u16* __restrict__ out,
                           int K, int N, int NT, int KS) {
    int tid = blockIdx.x * blockDim.x + threadIdx.x;
    if (tid >= NT * KS * 64) return;
    int l = tid & 63, ts = tid >> 6, s = ts % KS, t = ts / KS;
    int kb = s * 32 + ((l >> 4) << 3);
    int n = t * 16 + (l & 15);
    #pragma unroll
    for (int j = 0; j < 8; j++) {
        int k = kb + j;
        float v = (k < K && n < N) ? W[(size_t)k * N + n] : 0.f;
        out[(size_t)tid * 8 + j] = f2bf(v);
    }
}

// ---------------------------------------------------------------------------
// Per-node prep: xa = x @ A   and   agg = outer(x, attr) @ Wsc
// ---------------------------------------------------------------------------
template<int DI, int DO, int NT>
__global__ void node_prep(const float* __restrict__ xin,
                          const float* __restrict__ attr,
                          const float* __restrict__ A,
                          const float* __restrict__ Wsc,
                          float* __restrict__ xa,
                          float* __restrict__ agg)
{
    __shared__ float sx[NT][DI];
    __shared__ float sat[NT][ATTR];
    const int n0 = blockIdx.x * NT;
    for (int idx = threadIdx.x; idx < NT * DI; idx += blockDim.x)
        sx[idx / DI][idx % DI] = xin[(size_t)n0 * DI + idx];
    if (threadIdx.x < NT * ATTR)
        sat[threadIdx.x / ATTR][threadIdx.x % ATTR] = attr[(size_t)n0 * ATTR + threadIdx.x];
    __syncthreads();

    const int o = threadIdx.x;
    if (o < DO) {
        float at[NT][ATTR];
        #pragma unroll
        for (int n = 0; n < NT; n++) {
            at[n][0] = sat[n][0]; at[n][1] = sat[n][1];
            at[n][2] = sat[n][2]; at[n][3] = sat[n][3];
        }
        float accA[NT], accS[NT];
        #pragma unroll
        for (int n = 0; n < NT; n++) { accA[n] = 0.f; accS[n] = 0.f; }
        for (int i = 0; i < DI; i++) {
            float a  = A[(size_t)i * DO + o];
            float w0 = Wsc[(size_t)(i * 4 + 0) * DO + o];
            float w1 = Wsc[(size_t)(i * 4 + 1) * DO + o];
            float w2 = Wsc[(size_t)(i * 4 + 2) * DO + o];
            float w3 = Wsc[(size_t)(i * 4 + 3) * DO + o];
            #pragma unroll
            for (int n = 0; n < NT; n++) {
                float xi = sx[n][i];
                accA[n] = fmaf(xi, a, accA[n]);
                float s = fmaf(at[n][3], w3,
                          fmaf(at[n][2], w2,
                          fmaf(at[n][1], w1, at[n][0] * w0)));
                accS[n] = fmaf(xi, s, accS[n]);
            }
        }
        #pragma unroll
        for (int n = 0; n < NT; n++) {
            xa [(size_t)(n0 + n) * DO + o] = accA[n];
            agg[(size_t)(n0 + n) * DO + o] = accS[n];
        }
    }
}

// ---------------------------------------------------------------------------
// MFMA edge kernel. R7-exact dataflow (xv[36] f32 hoisted; single wait point)
// EXCEPT:
//  (a) t3 expanded as 9 static macro-steps with sched_barrier(0) after steps
//      2 and 5: caps the weight-fragment hoist window at ~15 frags (60 VGPR)
//      instead of 45 (180) — R7's VGPR=252 -> target <=170 for 3 waves/SIMD.
//  (b) rcp-silu (proven R8/R9).
// NEVER __launch_bounds__ min-waves > 2 here (R2: VGPR 84 spill; R8: same).
// Fragment layouts: A row=lane&15,k=(lane>>4)*8+j ; C/D col=lane&15,row=(lane>>4)*4+reg
// ---------------------------------------------------------------------------
#define T3STEP(T3)                                                             \
    {                                                                          \
        f32x4 shb = mfma16(a_sh, bff[(T3) * 64 + l], Z4);                      \
        f32x4 acc = mfma16(a_h2_0, w3f[((T3) * 4 + 0) * 64 + l], Z4);          \
        acc = mfma16(a_h2_1, w3f[((T3) * 4 + 1) * 64 + l], acc);               \
        acc = mfma16(a_h2_2, w3f[((T3) * 4 + 2) * 64 + l], acc);               \
        acc = mfma16(a_h2_3, w3f[((T3) * 4 + 3) * 64 + l], acc);               \
        const int n = (T3) * 16 + c;                                           \
        float v0 = acc[0] * shb[0] * xv[(T3) * 4 + 0] * INV_SQRT_NB;           \
        float v1 = acc[1] * shb[1] * xv[(T3) * 4 + 1] * INV_SQRT_NB;           \
        float v2 = acc[2] * shb[2] * xv[(T3) * 4 + 2] * INV_SQRT_NB;           \
        float v3 = acc[3] * shb[3] * xv[(T3) * 4 + 3] * INV_SQRT_NB;           \
        int m0 = g * 4;                                                        \
        int d0 = ((m0 + 0) * 96 + (n >> 1)) ^ (((m0 + 0) & 7) << 2);           \
        int d1 = ((m0 + 1) * 96 + (n >> 1)) ^ (((m0 + 1) & 7) << 2);           \
        int d2 = ((m0 + 2) * 96 + (n >> 1)) ^ (((m0 + 2) & 7) << 2);           \
        int d3 = ((m0 + 3) * 96 + (n >> 1)) ^ (((m0 + 3) & 7) << 2);           \
        ((u16*)(h2dw + d0))[n & 1] = f2bf(v0);                                 \
        ((u16*)(h2dw + d1))[n & 1] = f2bf(v1);                                 \
        ((u16*)(h2dw + d2))[n & 1] = f2bf(v2);                                 \
        ((u16*)(h2dw + d3))[n & 1] = f2bf(v3);                                 \
    }

template<int DO>
__global__ void __launch_bounds__(256)
edge_mfma(const float* __restrict__ emb, const float* __restrict__ sh,
          const int* __restrict__ src, const int* __restrict__ pos,
          const u16* __restrict__ W1f, const u16* __restrict__ W2f,
          const u16* __restrict__ W3f, const u16* __restrict__ Bf,
          const float* __restrict__ xa, u32* __restrict__ msgdw,
          float* __restrict__ msg3)
{
    __shared__ u32 ldsa[4 * 2400];        // 9600 B per wave, 38400 B/block
    const int wid = threadIdx.x >> 6;
    const int l   = threadIdx.x & 63;
    u32* Wl = ldsa + wid * 2400;
    float* embL  = (float*)Wl;            // [16][10] f32  (dw   0..159)
    float* shL   = (float*)(Wl + 160);    // [16][9]  f32  (dw 160..303)
    int*   sidxL = (int*)(Wl + 304);      // [16]
    int*   posL  = (int*)(Wl + 320);      // [16]          (pad to 352)
    u32*   h1dw  = Wl + 352;              // [16][32] dw = bf16 [16][64]
    u32*   h2dw  = Wl + 864;              // [16][64] dw h2, reused as [16][96] dw msg

    const bfrag8* w1f = (const bfrag8*)W1f;
    const bfrag8* w2f = (const bfrag8*)W2f;
    const bfrag8* w3f = (const bfrag8*)W3f;
    const bfrag8* bff = (const bfrag8*)Bf;

    const int g = l >> 4, c = l & 15;
    const int gwave = blockIdx.x * 4 + wid;
    const int nwave = gridDim.x * 4;
    const f32x4 Z4 = {0.f, 0.f, 0.f, 0.f};

    for (int it = gwave; it < NE / 16; it += nwave) {
        const int e0 = it * 16;
        // ---- stage emb/sh/idx (direct global->LDS) ----
        {
            const float* ep = emb + (size_t)e0 * NB;
            for (int idx = l; idx < 16 * NB; idx += 64) embL[idx] = ep[idx];
            const float* sp = sh + (size_t)e0 * DSH;
            for (int idx = l; idx < 16 * DSH; idx += 64) shL[idx] = sp[idx];
            if (l < 16) { sidxL[l] = src[e0 + l]; posL[l] = pos[e0 + l]; }
        }
        // ---- read src indices; issue ALL xa-gather loads up front ----
        const int si0 = sidxL[g * 4 + 0], si1 = sidxL[g * 4 + 1];
        const int si2 = sidxL[g * 4 + 2], si3 = sidxL[g * 4 + 3];
        float xv[(DO == 144) ? 36 : 1];
        if constexpr (DO == 144) {
            const float* xr0 = xa + (size_t)si0 * 144;
            const float* xr1 = xa + (size_t)si1 * 144;
            const float* xr2 = xa + (size_t)si2 * 144;
            const float* xr3 = xa + (size_t)si3 * 144;
            #pragma unroll
            for (int t3 = 0; t3 < 9; t3++) {
                xv[t3 * 4 + 0] = xr0[t3 * 16 + c];
                xv[t3 * 4 + 1] = xr1[t3 * 16 + c];
                xv[t3 * 4 + 2] = xr2[t3 * 16 + c];
                xv[t3 * 4 + 3] = xr3[t3 * 16 + c];
            }
        }
        // ---- A-frag of emb (K padded 10->32) ----
        bfrag8 a_emb;
        {
            const int kb = g << 3;
            #pragma unroll
            for (int j = 0; j < 8; j++) {
                int k = kb + j;
                float v = (k < NB) ? embL[c * NB + k] : 0.f;
                a_emb[j] = (short)f2bf(v);
            }
        }
        // ---- phase A: h1 = silu(emb @ W1), 4 MFMA -> LDS ----
        #pragma unroll
        for (int t = 0; t < 4; t++) {
            f32x4 acc = mfma16(a_emb, w1f[t * 64 + l], Z4);
            #pragma unroll
            for (int r = 0; r < 4; r++) {
                int m = g * 4 + r, n = t * 16 + c;
                int dw = (m * 32 + (n >> 1)) ^ ((m & 7) << 2);
                ((u16*)(h1dw + dw))[n & 1] = f2bf(silu_f(acc[r]));
            }
        }
        bfrag8 a_h1_0, a_h1_1;
        {
            int bb = c * 32 + g * 4, xr = (c & 7) << 2;
            a_h1_0 = *(const bfrag8*)(h1dw + ((bb +  0) ^ xr));
            a_h1_1 = *(const bfrag8*)(h1dw + ((bb + 16) ^ xr));
        }
        // ---- phase B: h2 = silu(h1 @ W2), 16 MFMA -> LDS ----
        #pragma unroll
        for (int t2 = 0; t2 < 8; t2++) {
            f32x4 acc = mfma16(a_h1_0, w2f[(t2 * 2 + 0) * 64 + l], Z4);
            acc = mfma16(a_h1_1, w2f[(t2 * 2 + 1) * 64 + l], acc);
            #pragma unroll
            for (int r = 0; r < 4; r++) {
                int m = g * 4 + r, n = t2 * 16 + c;
                int dw = (m * 64 + (n >> 1)) ^ ((m & 7) << 2);
                ((u16*)(h2dw + dw))[n & 1] = f2bf(silu_f(acc[r]));
            }
        }
        bfrag8 a_h2_0, a_h2_1, a_h2_2, a_h2_3;
        {
            int bb = c * 64 + g * 4, xr = (c & 7) << 2;
            a_h2_0 = *(const bfrag8*)(h2dw + ((bb +  0) ^ xr));
            a_h2_1 = *(const bfrag8*)(h2dw + ((bb + 16) ^ xr));
            a_h2_2 = *(const bfrag8*)(h2dw + ((bb + 32) ^ xr));
            a_h2_3 = *(const bfrag8*)(h2dw + ((bb + 48) ^ xr));
        }
        // ---- A-frag of sh (K padded 9->32) ----
        bfrag8 a_sh;
        {
            const int kb = g << 3;
            #pragma unroll
            for (int j = 0; j < 8; j++) {
                int k = kb + j;
                float v = (k < DSH) ? shL[c * DSH + k] : 0.f;
                a_sh[j] = (short)f2bf(v);
            }
        }

        if constexpr (DO == 144) {
            // ---- phases C+D: 9 static steps; sched_barrier(0) caps the
            //      fragment-hoist window at 3 steps (~15 frags, 60 VGPR) ----
            T3STEP(0) T3STEP(1) T3STEP(2)
            __builtin_amdgcn_sched_barrier(0);
            T3STEP(3) T3STEP(4) T3STEP(5)
            __builtin_amdgcn_sched_barrier(0);
            T3STEP(6) T3STEP(7) T3STEP(8)
            // ---- coalesced copy-out, slot-ordered rows ----
            for (int i = l; i < 1152; i += 64) {
                int m = i / 72;
                int xq = i - m * 72;
                u32 v = h2dw[(m * 96 + xq) ^ ((m & 7) << 2)];
                msgdw[(size_t)posL[m] * 72 + xq] = v;
            }
        } else {
            // ---- DO==3: single padded N-tile, direct f32 stores ----
            const int p0 = posL[g * 4 + 0], p1 = posL[g * 4 + 1];
            const int p2 = posL[g * 4 + 2], p3 = posL[g * 4 + 3];
            f32x4 shb = mfma16(a_sh, bff[l], Z4);
            f32x4 acc = mfma16(a_h2_0, w3f[0 * 64 + l], Z4);
            acc = mfma16(a_h2_1, w3f[1 * 64 + l], acc);
            acc = mfma16(a_h2_2, w3f[2 * 64 + l], acc);
            acc = mfma16(a_h2_3, w3f[3 * 64 + l], acc);
            if (c < 3) {
                msg3[(size_t)p0 * 3 + c] = acc[0] * shb[0] * xa[(size_t)si0 * 3 + c] * INV_SQRT_NB;
                msg3[(size_t)p1 * 3 + c] = acc[1] * shb[1] * xa[(size_t)si1 * 3 + c] * INV_SQRT_NB;
                msg3[(size_t)p2 * 3 + c] = acc[2] * shb[2] * xa[(size_t)si2 * 3 + c] * INV_SQRT_NB;
                msg3[(size_t)p3 * 3 + c] = acc[3] * shb[3] * xa[(size_t)si3 * 3 + c] * INV_SQRT_NB;
            }
        }
    }
}

// ---------------------------------------------------------------------------
// Streaming gather: msg is slot-ordered; node n's messages are rows
// ptr[n]..ptr[n+1] — fully sequential reads. Wave per node.
// ---------------------------------------------------------------------------
template<int ACT>
__global__ void gather144(const u32* __restrict__ msgdw,
                          const int* __restrict__ ptr,
                          const float* __restrict__ sc,
                          float* __restrict__ outb)
{
    const int lane = threadIdx.x & 63;
    const int gw = blockIdx.x * (blockDim.x >> 6) + (threadIdx.x >> 6);
    const int nw = gridDim.x * (blockDim.x >> 6);
    for (int n = gw; n < NN; n += nw) {
        const int s0 = ptr[n], s1 = ptr[n + 1];
        float a0 = 0.f, a1 = 0.f, b0 = 0.f, b1 = 0.f;
        for (int s = s0; s < s1; s++) {
            u32 u = msgdw[(size_t)s * 72 + lane];
            a0 += __uint_as_float(u << 16);
            a1 += __uint_as_float(u & 0xffff0000u);
            if (lane < 8) {
                u32 v = msgdw[(size_t)s * 72 + 64 + lane];
                b0 += __uint_as_float(v << 16);
                b1 += __uint_as_float(v & 0xffff0000u);
            }
        }
        size_t base = (size_t)n * 144;
        float2 sv = *(const float2*)&sc[base + 2 * lane];
        float v0 = sv.x + a0, v1 = sv.y + a1;
        if (ACT) { v0 = silu_f(v0); v1 = silu_f(v1); }
        *(float2*)&outb[base + 2 * lane] = make_float2(v0, v1);
        if (lane < 8) {
            float2 sw = *(const float2*)&sc[base + 128 + 2 * lane];
            float w0 = sw.x + b0, w1 = sw.y + b1;
            if (ACT) { w0 = silu_f(w0); w1 = silu_f(w1); }
            *(float2*)&outb[base + 128 + 2 * lane] = make_float2(w0, w1);
        }
    }
}

__global__ void gather3(const float* __restrict__ msg3,
                        const int* __restrict__ ptr,
                        float* __restrict__ outb)
{
    int t = blockIdx.x * blockDim.x + threadIdx.x;
    if (t >= NN * 3) return;
    int n = t / 3, o = t - 3 * n;
    float a = 0.f;
    for (int s = ptr[n]; s < ptr[n + 1]; s++) a += msg3[(size_t)s * 3 + o];
    outb[t] += a;   // self-connection already written by node_prep
}

// ---------------------------------------------------------------------------
extern "C" void kernel_launch(void* const* d_in, const int* in_sizes, int n_in,
                              void* d_out, int out_size, void* d_ws, size_t ws_size,
                              hipStream_t stream) {
    const float* x    = (const float*)d_in[0];
    const float* attr = (const float*)d_in[1];
    const float* sh   = (const float*)d_in[2];
    const float* emb  = (const float*)d_in[3];
    const float* A0   = (const float*)d_in[4];
    const float* B0   = (const float*)d_in[5];
    const float* W1_0 = (const float*)d_in[6];
    const float* W2_0 = (const float*)d_in[7];
    const float* W3_0 = (const float*)d_in[8];
    const float* Wsc0 = (const float*)d_in[9];
    const float* A1   = (const float*)d_in[10];
    const float* B1   = (const float*)d_in[11];
    const float* W1_1 = (const float*)d_in[12];
    const float* W2_1 = (const float*)d_in[13];
    const float* W3_1 = (const float*)d_in[14];
    const float* Wsc1 = (const float*)d_in[15];
    const float* A2   = (const float*)d_in[16];
    const float* B2   = (const float*)d_in[17];
    const float* W1_2 = (const float*)d_in[18];
    const float* W2_2 = (const float*)d_in[19];
    const float* W3_2 = (const float*)d_in[20];
    const float* Wsc2 = (const float*)d_in[21];
    const int*   src  = (const int*)d_in[22];
    const int*   dst  = (const int*)d_in[23];
    float* out = (float*)d_out;

    // ---- carve workspace ----
    char* wp = (char*)d_ws;
    auto alloc = [&](size_t bytes) -> void* {
        void* r = (void*)wp;
        wp += (bytes + 255) & ~(size_t)255;
        return r;
    };
    float* xa   = (float*)alloc((size_t)NN * 144 * 4);
    float* agg  = (float*)alloc((size_t)NN * 144 * 4);
    float* hb0  = (float*)alloc((size_t)NN * 144 * 4);
    float* hb1  = (float*)alloc((size_t)NN * 144 * 4);
    int*   cnt  = (int*)alloc((size_t)NN * 4);
    int*   ptr  = (int*)alloc((size_t)(NN + 1) * 4);
    int*   pos  = (int*)alloc((size_t)NE * 4);
    u16* w1f0 = (u16*)alloc(4 * 64 * 8 * 2);
    u16* w2f0 = (u16*)alloc(16 * 64 * 8 * 2);
    u16* w3f0 = (u16*)alloc(36 * 64 * 8 * 2);
    u16* bf0  = (u16*)alloc(9 * 64 * 8 * 2);
    u16* w1f1 = (u16*)alloc(4 * 64 * 8 * 2);
    u16* w2f1 = (u16*)alloc(16 * 64 * 8 * 2);
    u16* w3f1 = (u16*)alloc(36 * 64 * 8 * 2);
    u16* bf1  = (u16*)alloc(9 * 64 * 8 * 2);
    u16* w1f2 = (u16*)alloc(4 * 64 * 8 * 2);
    u16* w2f2 = (u16*)alloc(16 * 64 * 8 * 2);
    u16* w3f2 = (u16*)alloc(4 * 64 * 8 * 2);
    u16* bf2  = (u16*)alloc(1 * 64 * 8 * 2);
    void* msgbuf = alloc((size_t)NE * 288);      // bf16 [E][144] == u32 [E][72]
    u32*   msgdw = (u32*)msgbuf;
    float* msg3  = (float*)msgbuf;               // layer-2 f32 [E][3] aliases

    // ---- CSR build (dst identical across layers) ----
    hipMemsetAsync(cnt, 0, (size_t)NN * 4, stream);
    count_k<<<1024, 256, 0, stream>>>(dst, cnt);
    scan_k<<<1, 256, 0, stream>>>(cnt, ptr);
    hipMemsetAsync(cnt, 0, (size_t)NN * 4, stream);
    fill_k<<<1024, 256, 0, stream>>>(dst, ptr, cnt, pos);

    // ---- weight fragment packing ----
    pack_bfrag<<<1, 256, 0, stream>>>(W1_0, w1f0, 10, 64, 4, 1);
    pack_bfrag<<<4, 256, 0, stream>>>(W2_0, w2f0, 64, 128, 8, 2);
    pack_bfrag<<<9, 256, 0, stream>>>(W3_0, w3f0, 128, 144, 9, 4);
    pack_bfrag<<<3, 256, 0, stream>>>(B0,   bf0,  9, 144, 9, 1);
    pack_bfrag<<<1, 256, 0, stream>>>(W1_1, w1f1, 10, 64, 4, 1);
    pack_bfrag<<<4, 256, 0, stream>>>(W2_1, w2f1, 64, 128, 8, 2);
    pack_bfrag<<<9, 256, 0, stream>>>(W3_1, w3f1, 128, 144, 9, 4);
    pack_bfrag<<<3, 256, 0, stream>>>(B1,   bf1,  9, 144, 9, 1);
    pack_bfrag<<<1, 256, 0, stream>>>(W1_2, w1f2, 10, 64, 4, 1);
    pack_bfrag<<<4, 256, 0, stream>>>(W2_2, w2f2, 64, 128, 8, 2);
    pack_bfrag<<<1, 256, 0, stream>>>(W3_2, w3f2, 128, 3, 1, 4);
    pack_bfrag<<<1, 256, 0, stream>>>(B2,   bf2,  9, 3, 1, 1);

    // ---- layer 0 (di=64, do=144) ----
    node_prep<64, 144, 8><<<NN / 8, 192, 0, stream>>>(x, attr, A0, Wsc0, xa, agg);
    edge_mfma<144><<<2500, 256, 0, stream>>>(emb, sh, src, pos, w1f0, w2f0, w3f0, bf0, xa, msgdw, nullptr);
    gather144<1><<<5000, 256, 0, stream>>>(msgdw, ptr, agg, hb0);

    // ---- layer 1 (di=144, do=144) ----
    node_prep<144, 144, 8><<<NN / 8, 192, 0, stream>>>(hb0, attr, A1, Wsc1, xa, agg);
    edge_mfma<144><<<2500, 256, 0, stream>>>(emb, sh, src, pos, w1f1, w2f1, w3f1, bf1, xa, msgdw, nullptr);
    gather144<1><<<5000, 256, 0, stream>>>(msgdw, ptr, agg, hb1);

    // ---- layer 2 (di=144, do=3) ----
    node_prep<144, 3, 8><<<NN / 8, 192, 0, stream>>>(hb1, attr, A2, Wsc2, xa, out);
    edge_mfma<3><<<2500, 256, 0, stream>>>(emb, sh, src, pos, w1f2, w2f2, w3f2, bf2, xa, nullptr, msg3);
    gather3<<<(NN * 3 + 255) / 256, 256, 0, stream>>>(msg3, ptr, out);
}